// Round 14
// baseline (39.736 us; speedup 1.0000x reference)
//
#include <hip/hip_runtime.h>
#include <hip/hip_bf16.h>
#include <math.h>

#define T 4000
#define C 128
#define NB 800                 // T/5
#define NSTRIPE 25             // T/160 stripes of 160 i-rows
#define KSPLIT 25              // k-slices; NT=10 k-tiles per block
#define NT 10
#define CFRAC (1598.0f/3995.0f)

typedef short bf16x8 __attribute__((ext_vector_type(8)));
typedef float f32x4 __attribute__((ext_vector_type(4)));

// float -> bf16 bits, round-to-nearest-even
__device__ inline unsigned short f2bf(float f) {
    union { float f; unsigned u; } v; v.f = f;
    unsigned r = v.u + 0x7fffu + ((v.u >> 16) & 1u);
    return (unsigned short)(r >> 16);
}

__device__ inline bf16x8 pack8(const float4& u, const float4& v) {
    bf16x8 o;
    o[0] = (short)f2bf(u.x); o[1] = (short)f2bf(u.y);
    o[2] = (short)f2bf(u.z); o[3] = (short)f2bf(u.w);
    o[4] = (short)f2bf(v.x); o[5] = (short)f2bf(v.y);
    o[6] = (short)f2bf(v.z); o[7] = (short)f2bf(v.w);
    return o;
}

__device__ inline float sq8(const float4& u, const float4& v) {
    return u.x*u.x + u.y*u.y + u.z*u.z + u.w*u.w
         + v.x*v.x + v.y*v.y + v.z*v.z + v.w*v.w;
}

// ---------------- Kernel 1: fused norm + partial rowsums (single-phase) ----------------
// grid (NSTRIPE, KSPLIT) x 320 threads (5 waves x 32 i-rows = 160 rows/block).
// Stage all 10 B-tiles (40KB) from fp32 x, converting to bf16 in-reg; each slot
// also writes its 8-value sumsq partial to sNorm. ONE barrier; 160 threads fold
// sNorm -> sInv (inv col norms, off the MFMA critical path — r10's mistake was
// doing this VALU inside a 5-phase barrier loop). A-side: fp32 loads, sumsq via
// 2 shfl_xor folds (lane r,hi holds 32ch of row i0+r / i0+16+r), bf16 frags,
// post-MFMA scale acc*inv_i*inv_k before exp. No norm kernel, no xnb buffer.
// Frag layout: lane (r=lane&15, hi=lane>>4) holds row ..+r, ch kc*32+hi*8..+8.
// C/D frag: col k = lane&15 (=r), row i = hi*4+j (m89-verified).
__global__ __launch_bounds__(320) void rowsum_kernel(const float* __restrict__ x,
                                                     float* __restrict__ rpart,
                                                     float* __restrict__ out) {
    __shared__ __hip_bfloat16 sB[NT * 2048];   // 10 tiles x 4KB
    __shared__ float sNorm[NT * 16][16];       // per-row sumsq partials (16 slots/row)
    __shared__ float sInv[NT * 16];            // per-k-row inverse norms

    const int bi = blockIdx.x;      // stripe 0..24
    const int ks = blockIdx.y;      // k-slice 0..24
    const int tid = threadIdx.x;
    if (bi == 0 && ks == 0 && tid == 0) out[0] = 0.f;   // visible to K2 after boundary
    const int w = tid >> 6, lane = tid & 63;
    const int r = lane & 15, hi = lane >> 4;
    const int ko = hi * 8;
    const int i0 = bi * 160 + w * 32;
    const int kt0 = ks * NT;

    // ---- stage all 10 B-tiles: slot s = tid + rd*320 (lane-part == lane);
    //      tile=s>>8, wc=(s>>6)&3; covers every (tile,row,chunk) exactly once ----
#pragma unroll
    for (int rd = 0; rd < 8; ++rd) {
        const int s = tid + rd * 320;
        const int tile = s >> 8, wc = (s >> 6) & 3;
        const float* p = x + (size_t)(kt0 + tile) * 16 * C + (size_t)r * C + wc * 32 + ko;
        float4 u = *(const float4*)p;
        float4 v = *(const float4*)(p + 4);
        *(bf16x8*)&sB[s * 8] = pack8(u, v);
        sNorm[tile * 16 + r][wc * 4 + hi] = sq8(u, v);
    }

    // ---- A rows (fp32), inv norms, bf16 frags (overlaps staging latency) ----
    float ss0 = 0.f, ss1 = 0.f;
    bf16x8 afrag0[4], afrag1[4];
    const float* a0p = x + (size_t)(i0 + r) * C + ko;
    const float* a1p = x + (size_t)(i0 + 16 + r) * C + ko;
#pragma unroll
    for (int kc = 0; kc < 4; ++kc) {
        float4 u0 = *(const float4*)(a0p + kc * 32);
        float4 v0 = *(const float4*)(a0p + kc * 32 + 4);
        float4 u1 = *(const float4*)(a1p + kc * 32);
        float4 v1 = *(const float4*)(a1p + kc * 32 + 4);
        ss0 += sq8(u0, v0); ss1 += sq8(u1, v1);
        afrag0[kc] = pack8(u0, v0); afrag1[kc] = pack8(u1, v1);
    }
    ss0 += __shfl_xor(ss0, 16); ss0 += __shfl_xor(ss0, 32);
    ss1 += __shfl_xor(ss1, 16); ss1 += __shfl_xor(ss1, 32);
    const float invr0 = 1.0f / fmaxf(sqrtf(ss0), 1e-8f);
    const float invr1 = 1.0f / fmaxf(sqrtf(ss1), 1e-8f);
    float invi0[4], invi1[4];
#pragma unroll
    for (int j = 0; j < 4; ++j) {
        invi0[j] = __shfl(invr0, hi * 4 + j);   // inv-norm of C/D row hi*4+j (set 0)
        invi1[j] = __shfl(invr1, hi * 4 + j);   // set 1 (rows +16)
    }

    __syncthreads();

    // ---- fold sNorm -> sInv (160 threads, off critical path) ----
    if (tid < NT * 16) {
        const f32x4* q = (const f32x4*)sNorm[tid];
        f32x4 s4 = q[0] + q[1] + q[2] + q[3];
        float s = s4[0] + s4[1] + s4[2] + s4[3];
        sInv[tid] = 1.0f / fmaxf(sqrtf(s), 1e-8f);
    }
    __syncthreads();

    // ---- compute: 10 tiles of uninterrupted ds_read/MFMA, post-scale, exp ----
    f32x4 rsum0 = {0.f, 0.f, 0.f, 0.f}, rsum1 = {0.f, 0.f, 0.f, 0.f};
#pragma unroll 2
    for (int t = 0; t < NT; ++t) {
        f32x4 a0 = {0.f, 0.f, 0.f, 0.f}, a1 = {0.f, 0.f, 0.f, 0.f};
#pragma unroll
        for (int kc = 0; kc < 4; ++kc) {
            bf16x8 bf = *(bf16x8*)&sB[t * 2048 + kc * 512 + lane * 8];
            a0 = __builtin_amdgcn_mfma_f32_16x16x32_bf16(afrag0[kc], bf, a0, 0, 0, 0);
            a1 = __builtin_amdgcn_mfma_f32_16x16x32_bf16(afrag1[kc], bf, a1, 0, 0, 0);
        }
        const float invk = sInv[t * 16 + r];    // col k of this lane = r
#pragma unroll
        for (int j = 0; j < 4; ++j) {
            rsum0[j] += __expf(a0[j] * (invi0[j] * invk));
            rsum1[j] += __expf(a1[j] * (invi1[j] * invk));
        }
    }

    // fold the 16 k-columns (lane bits 0..3), keep hi groups separate
#pragma unroll
    for (int off = 1; off < 16; off <<= 1)
#pragma unroll
        for (int j = 0; j < 4; ++j) {
            rsum0[j] += __shfl_xor(rsum0[j], off);
            rsum1[j] += __shfl_xor(rsum1[j], off);
        }

    if (r == 0) {
        *(f32x4*)(rpart + (size_t)ks * T + i0 + hi * 4) = rsum0;
        *(f32x4*)(rpart + (size_t)ks * T + i0 + 16 + hi * 4) = rsum1;
    }
}

// ---------------- Kernel 2: per-5-block loss (one block per 5-block) ----------------
__global__ __launch_bounds__(64) void loss_kernel(const float* __restrict__ x,
                                                  const float* __restrict__ rpart,
                                                  const int* __restrict__ kuai2p,
                                                  float* __restrict__ out) {
    __shared__ float xs[5][C];
    __shared__ float d[5][5];
    __shared__ float rsp[5][5];
    const int b = blockIdx.x;
    const int base = b * 5;
    const int t = threadIdx.x;

    // cooperative rowsum gather: thread t<25 sums 5 partials for row t/5
    if (t < 25) {
        int pr = t / 5, chunk = t % 5;
        float s = 0.f;
#pragma unroll
        for (int k2 = 0; k2 < 5; ++k2)
            s += rpart[(size_t)(chunk * 5 + k2) * T + base + pr];
        rsp[pr][chunk] = s;
    }

    // load 5 raw fp32 rows (160 float4)
    for (int i = t; i < 160; i += 64) {
        int row = i >> 5, c4 = i & 31;
        *(float4*)&xs[row][c4 * 4] = *(const float4*)(x + (size_t)(base + row) * C + c4 * 4);
    }
    __syncthreads();

    // 25 dots, 2 threads per pair (half the channels each), float4 vectorized
    if (t < 50) {
        int p = t >> 1, half = t & 1;
        int pi = p / 5, pj = p % 5;
        float s = 0.f;
        const float* xa = &xs[pi][half * 64];
        const float* xb = &xs[pj][half * 64];
#pragma unroll
        for (int c4 = 0; c4 < 16; ++c4) {
            float4 a4 = *(const float4*)(xa + c4 * 4);
            float4 b4 = *(const float4*)(xb + c4 * 4);
            s += a4.x * b4.x + a4.y * b4.y + a4.z * b4.z + a4.w * b4.w;
        }
        s += __shfl_xor(s, 1);
        if (half == 0) d[pi][pj] = s;
    }
    __syncthreads();

    float contrib = 0.f;
    if (t < 20) {
        int pi = t >> 2, rr = t & 3;
        int pj = rr + (rr >= pi ? 1 : 0);
        float sii = d[pi][pi];
        float bsum = 0.f, sij = 0.f;
#pragma unroll
        for (int m = 0; m < 5; ++m) {
            float s = d[pi][m] * rsqrtf(sii * d[m][m]);   // cosine sim, fp32
            bsum += __expf(s);
            if (m == pj) sij = s;
        }
        float rs = rsp[pi][0] + rsp[pi][1] + rsp[pi][2] + rsp[pi][3] + rsp[pi][4];
        float negE = CFRAC * (rs - bsum);                 // E[neg_sum]
        contrib = sij - __logf(negE + __expf(sij));       // log(pos/(neg+pos))
    }
#pragma unroll
    for (int off = 32; off; off >>= 1) contrib += __shfl_xor(contrib, off);

    if (t == 0) {
        int k = *kuai2p;
        atomicAdd(out, contrib * (-1.0f / ((float)NB * (float)k * (float)(k - 1))));
    }
}

extern "C" void kernel_launch(void* const* d_in, const int* in_sizes, int n_in,
                              void* d_out, int out_size, void* d_ws, size_t ws_size,
                              hipStream_t stream) {
    const float* x = (const float*)d_in[0];
    const int* kuai2 = (const int*)d_in[1];
    float* out = (float*)d_out;

    float* rpart = (float*)d_ws;             // KSPLIT*T floats = 400 KB

    dim3 g1(NSTRIPE, KSPLIT);
    rowsum_kernel<<<g1, 320, 0, stream>>>(x, rpart, out);

    loss_kernel<<<NB, 64, 0, stream>>>(x, rpart, kuai2, out);
}

// Round 15
// 34.581 us; speedup vs baseline: 1.1491x; 1.1491x over previous
//
#include <hip/hip_runtime.h>
#include <hip/hip_bf16.h>
#include <math.h>

#define T 4000
#define C 128
#define NB 800                 // T/5
#define NSTRIPE 25             // T/160 stripes of 160 i-rows
#define KSPLIT 25              // k-slices; NT=10 k-tiles per block
#define NT 10
#define CFRAC (1598.0f/3995.0f)

typedef short bf16x8 __attribute__((ext_vector_type(8)));
typedef float f32x4 __attribute__((ext_vector_type(4)));

// float -> bf16 bits, round-to-nearest-even (inputs are normal finite floats)
__device__ inline unsigned short f2bf(float f) {
    union { float f; unsigned u; } v; v.f = f;
    unsigned r = v.u + 0x7fffu + ((v.u >> 16) & 1u);
    return (unsigned short)(r >> 16);
}

// ---------------- Kernel 0: normalize rows -> bf16 xnb; zero out ----------------
__global__ __launch_bounds__(1024) void norm_kernel(const float* __restrict__ x,
                                                    __hip_bfloat16* __restrict__ xnb,
                                                    float* __restrict__ out) {
    if (blockIdx.x == 0 && threadIdx.x == 0) out[0] = 0.f;  // visible to K2 after boundary
    const int row = blockIdx.x * 16 + (threadIdx.x >> 6);
    const int lane = threadIdx.x & 63;
    const float* xr = x + (size_t)row * C;
    float2 v = *(const float2*)(xr + lane * 2);
    float ss = v.x * v.x + v.y * v.y;
    for (int off = 32; off; off >>= 1) ss += __shfl_xor(ss, off);
    float inv = 1.0f / fmaxf(sqrtf(ss), 1e-8f);
    unsigned o = (unsigned)f2bf(v.x * inv) | ((unsigned)f2bf(v.y * inv) << 16);
    *(unsigned*)((unsigned short*)xnb + (size_t)row * C + lane * 2) = o;
}

// ---------------- Kernel 1: partial rowsums; W=32 rows/wave ----------------
// grid (NSTRIPE, KSPLIT) x 320 threads (5 waves x 32 i-rows = 160 rows/block).
// Each wave holds TWO A-frag sets (rows w*32+{r, 16+r}), so each B ds_read_b128
// feeds 2 MFMAs. Single-phase staging: all 10 B-tiles (40KB) loaded (frag-order
// gather) then one barrier, then uninterrupted ds_read/MFMA/exp.
// Frag layout: lane (r=lane&15, hi=lane>>4) holds row ..+r, ch kc*32+hi*8..+8.
// C/D frag: col k = lane&15, row i = hi*4+j (m89-verified).
__global__ __launch_bounds__(320) void rowsum_kernel(const __hip_bfloat16* __restrict__ xnb,
                                                     float* __restrict__ rpart) {
    __shared__ __hip_bfloat16 sB[NT * 2048];   // 10 tiles x 4KB

    const int bi = blockIdx.x;      // stripe 0..24
    const int ks = blockIdx.y;      // k-slice 0..24
    const int tid = threadIdx.x;
    const int w = tid >> 6, lane = tid & 63;
    const int r = lane & 15, hi = lane >> 4;
    const int ko = hi * 8;
    const int i0 = bi * 160 + w * 32;
    const int kt0 = ks * NT;

    // ---- stage all 10 B-tiles: slot s = tid + rd*320; tile=s>>8, chunk=(s>>6)&3;
    //      lane-part of s is always `lane` (320 % 64 == 0). Issue all loads first. ----
    const __hip_bfloat16* bbase = xnb + (size_t)kt0 * 16 * C + (size_t)r * C + ko;
    bf16x8 st[8];
#pragma unroll
    for (int rd = 0; rd < 8; ++rd) {
        const int s = tid + rd * 320;
        const int tile = s >> 8, wc = (s >> 6) & 3;
        st[rd] = *(const bf16x8*)(bbase + tile * 16 * C + wc * 32);
    }

    // A frags (2 sets), loaded while B is in flight
    bf16x8 afrag0[4], afrag1[4];
    const __hip_bfloat16* arow0 = xnb + (size_t)(i0 + r) * C;
    const __hip_bfloat16* arow1 = xnb + (size_t)(i0 + 16 + r) * C;
#pragma unroll
    for (int kc = 0; kc < 4; ++kc) {
        afrag0[kc] = *(const bf16x8*)(arow0 + kc * 32 + ko);
        afrag1[kc] = *(const bf16x8*)(arow1 + kc * 32 + ko);
    }

#pragma unroll
    for (int rd = 0; rd < 8; ++rd) {
        const int s = tid + rd * 320;
        *(bf16x8*)&sB[s * 8] = st[rd];   // flat dest: tile*2048 + wc*512 + lane*8
    }
    __syncthreads();   // the ONLY barrier

    f32x4 rsum0 = {0.f, 0.f, 0.f, 0.f}, rsum1 = {0.f, 0.f, 0.f, 0.f};
#pragma unroll 2
    for (int t = 0; t < NT; ++t) {
        f32x4 a0 = {0.f, 0.f, 0.f, 0.f}, a1 = {0.f, 0.f, 0.f, 0.f};
#pragma unroll
        for (int kc = 0; kc < 4; ++kc) {
            bf16x8 bf = *(bf16x8*)&sB[t * 2048 + kc * 512 + lane * 8];
            a0 = __builtin_amdgcn_mfma_f32_16x16x32_bf16(afrag0[kc], bf, a0, 0, 0, 0);
            a1 = __builtin_amdgcn_mfma_f32_16x16x32_bf16(afrag1[kc], bf, a1, 0, 0, 0);
        }
#pragma unroll
        for (int j = 0; j < 4; ++j) {
            rsum0[j] += __expf(a0[j]);
            rsum1[j] += __expf(a1[j]);
        }
    }

    // fold the 16 k-columns (lane bits 0..3), keep hi groups separate
#pragma unroll
    for (int off = 1; off < 16; off <<= 1)
#pragma unroll
        for (int j = 0; j < 4; ++j) {
            rsum0[j] += __shfl_xor(rsum0[j], off);
            rsum1[j] += __shfl_xor(rsum1[j], off);
        }

    if (r == 0) {
        *(f32x4*)(rpart + (size_t)ks * T + i0 + hi * 4) = rsum0;
        *(f32x4*)(rpart + (size_t)ks * T + i0 + 16 + hi * 4) = rsum1;
    }
}

// ---------------- Kernel 2: per-5-block loss (one block per 5-block) ----------------
__global__ __launch_bounds__(64) void loss_kernel(const float* __restrict__ x,
                                                  const float* __restrict__ rpart,
                                                  const int* __restrict__ kuai2p,
                                                  float* __restrict__ out) {
    __shared__ float xs[5][C];
    __shared__ float d[5][5];
    __shared__ float rsp[5][5];
    const int b = blockIdx.x;
    const int base = b * 5;
    const int t = threadIdx.x;

    // cooperative rowsum gather: thread t<25 sums 5 partials for row t/5
    if (t < 25) {
        int pr = t / 5, chunk = t % 5;
        float s = 0.f;
#pragma unroll
        for (int k2 = 0; k2 < 5; ++k2)
            s += rpart[(size_t)(chunk * 5 + k2) * T + base + pr];
        rsp[pr][chunk] = s;
    }

    // load 5 raw fp32 rows (160 float4)
    for (int i = t; i < 160; i += 64) {
        int row = i >> 5, c4 = i & 31;
        *(float4*)&xs[row][c4 * 4] = *(const float4*)(x + (size_t)(base + row) * C + c4 * 4);
    }
    __syncthreads();

    // 25 dots, 2 threads per pair (half the channels each), float4 vectorized
    if (t < 50) {
        int p = t >> 1, half = t & 1;
        int pi = p / 5, pj = p % 5;
        float s = 0.f;
        const float* xa = &xs[pi][half * 64];
        const float* xb = &xs[pj][half * 64];
#pragma unroll
        for (int c4 = 0; c4 < 16; ++c4) {
            float4 a4 = *(const float4*)(xa + c4 * 4);
            float4 b4 = *(const float4*)(xb + c4 * 4);
            s += a4.x * b4.x + a4.y * b4.y + a4.z * b4.z + a4.w * b4.w;
        }
        s += __shfl_xor(s, 1);
        if (half == 0) d[pi][pj] = s;
    }
    __syncthreads();

    float contrib = 0.f;
    if (t < 20) {
        int pi = t >> 2, rr = t & 3;
        int pj = rr + (rr >= pi ? 1 : 0);
        float sii = d[pi][pi];
        float bsum = 0.f, sij = 0.f;
#pragma unroll
        for (int m = 0; m < 5; ++m) {
            float s = d[pi][m] * rsqrtf(sii * d[m][m]);   // cosine sim, fp32
            bsum += __expf(s);
            if (m == pj) sij = s;
        }
        float rs = rsp[pi][0] + rsp[pi][1] + rsp[pi][2] + rsp[pi][3] + rsp[pi][4];
        float negE = CFRAC * (rs - bsum);                 // E[neg_sum]
        contrib = sij - __logf(negE + __expf(sij));       // log(pos/(neg+pos))
    }
#pragma unroll
    for (int off = 32; off; off >>= 1) contrib += __shfl_xor(contrib, off);

    if (t == 0) {
        int k = *kuai2p;
        atomicAdd(out, contrib * (-1.0f / ((float)NB * (float)k * (float)(k - 1))));
    }
}

extern "C" void kernel_launch(void* const* d_in, const int* in_sizes, int n_in,
                              void* d_out, int out_size, void* d_ws, size_t ws_size,
                              hipStream_t stream) {
    const float* x = (const float*)d_in[0];
    const int* kuai2 = (const int*)d_in[1];
    float* out = (float*)d_out;

    float* rpart = (float*)d_ws;                             // KSPLIT*T floats = 400 KB
    __hip_bfloat16* xnb = (__hip_bfloat16*)(rpart + KSPLIT * T);

    norm_kernel<<<T / 16, 1024, 0, stream>>>(x, xnb, out);

    dim3 g1(NSTRIPE, KSPLIT);
    rowsum_kernel<<<g1, 320, 0, stream>>>(xnb, rpart);

    loss_kernel<<<NB, 64, 0, stream>>>(x, rpart, kuai2, out);
}